// Round 4
// baseline (220.623 us; speedup 1.0000x reference)
//
#include <hip/hip_runtime.h>
#include <math.h>

// GCN on 50000 disjoint 21-node hand-skeleton graphs (fixed topology).
// Fused: aggregate-before-matmul, BN folded into W/b, pooling commuted past W3.
// R4: single-pass bf16 MFMA (error budget allows), trunc+v_perm bf16 packing,
// LUT-driven pooling epilogue with register per-graph accumulators, W3T read
// from global in phase 3, W1 interleaved float4.

#define G_TOTAL 50000
#define NPG 21
#define GPB 6
#define NCHUNK ((G_TOTAL + GPB - 1) / GPB)     // 8334
#define NCLS 29
#define BN_EPS 1e-5f
#define INV_SQRT2 0.70710678118654752440f
#define ROOT_COLSUM 4.53553390593273762f       // 1 + 5/sqrt(2)

// ws dword layout
#define WS_W1B  0              // 256: [k]{w0,w1,w2,b1f} float4-interleaved
#define WS_B2   256            // 128
#define WS_B3   384            // 32 (29 used)
#define WS_W3T  416            // 3712: W3T [29][128]
#define WS_BF   4128           // 4096: W2 B-frags, bf16 RNE, [n8][ss2][lane64][4dw]
#define WS_TOTAL (WS_BF + 4096)

typedef short s16x8 __attribute__((ext_vector_type(8)));
typedef float f32x4 __attribute__((ext_vector_type(4)));

__device__ __forceinline__ unsigned f2bf_rne(float f) {
    unsigned u = __float_as_uint(f);
    return (u + 0x7FFFu + ((u >> 16) & 1u)) >> 16;
}

__global__ void prep_kernel(const float* __restrict__ W1, const float* __restrict__ b1,
                            const float* __restrict__ g1, const float* __restrict__ be1,
                            const float* __restrict__ m1, const float* __restrict__ v1,
                            const float* __restrict__ W2, const float* __restrict__ b2,
                            const float* __restrict__ g2, const float* __restrict__ be2,
                            const float* __restrict__ m2, const float* __restrict__ v2,
                            const float* __restrict__ W3, const float* __restrict__ b3,
                            float* __restrict__ ws) {
    int t = blockIdx.x * blockDim.x + threadIdx.x;
    if (t < 256) {                              // W1B interleave
        int k = t >> 2, comp = t & 3;
        float s = g1[k] * rsqrtf(v1[k] + BN_EPS);
        float v;
        if (comp < 3) v = W1[comp * 64 + k] * s;
        else          v = (b1[k] - m1[k]) * s + be1[k];
        ws[WS_W1B + t] = v;
    } else if (t < 384) {                       // b2f
        int j = t - 256;
        float s = g2[j] * rsqrtf(v2[j] + BN_EPS);
        ws[WS_B2 + j] = (b2[j] - m2[j]) * s + be2[j];
    } else if (t < 416) {                       // b3 (pad 32)
        int j = t - 384;
        ws[WS_B3 + j] = (j < NCLS) ? b3[j] : 0.f;
    } else if (t < WS_BF) {                     // W3T[c][k] = W3[k*29+c]
        int i = t - WS_W3T;
        if (i < 3712) {
            int c = i >> 7, k = i & 127;
            ws[WS_W3T + i] = W3[k * NCLS + c];
        }
    } else if (t < WS_TOTAL) {                  // B-frags of W2f (bf16 RNE, single)
        int i = t - WS_BF;                      // dword index
        int d  = i & 3;
        int l  = (i >> 2) & 63;
        int ss = (i >> 8) & 1;
        int n  = i >> 9;                        // 0..7
        int kg = l >> 4, r = l & 15;
        int c = 16 * n + r;
        float sc = g2[c] * rsqrtf(v2[c] + BN_EPS);
        int k0 = 32 * ss + 8 * kg + 2 * d;
        unsigned h0 = f2bf_rne(W2[k0 * 128 + c] * sc);
        unsigned h1 = f2bf_rne(W2[(k0 + 1) * 128 + c] * sc);
        ((unsigned*)ws)[WS_BF + i] = (h1 << 16) | h0;
    }
}

__global__ __launch_bounds__(256, 4)
void gcn_main(const float* __restrict__ x, const float* __restrict__ ws,
              float* __restrict__ out) {
    // sZ: phase1 z1 fp32 [128 rows][stride 68]; phase2 A-frag alias (16 KB);
    // phase3 alias: sLg[176] @0, sRed[12] @192
    __shared__ __align__(16) float sZ[8704];
    __shared__ __align__(16) float4 sW1B[64];
    __shared__ float  sb2[128];
    __shared__ __align__(8) float2 sLUT[128];
    __shared__ float  sP[GPB * 128];

    const int tid = threadIdx.x;
    const int g0 = blockIdx.x * GPB;
    const int nv = min(GPB, G_TOTAL - g0);
    const int Mrows = nv * NPG;

    // ---- stage weights + row LUT ----
    if (tid < 64) sW1B[tid] = ((const float4*)ws)[tid];
    else if (tid < 192) sb2[tid - 64] = ws[WS_B2 + (tid - 64)];
    if (tid < 128) {
        const int r = tid;
        const int lg2 = (r * 3121) >> 16;       // r/21
        const int j = r - NPG * lg2;
        float w = (j == 0) ? (ROOT_COLSUM / 21.f)
                           : (((j & 3) == 0) ? (0.5f / 21.f) : (1.f / 21.f));
        if (r >= Mrows) w = 0.f;
        sLUT[r] = make_float2(w, (float)lg2);
    }
    __syncthreads();

    // ---- phase 1: z[node][k] = relu((A x)[node] . W1f + b1f) ----
    const int node = tid >> 1;          // 0..127
    const int s = tid & 1;
    const int k0 = s * 32;
    const int lg = (node * 3121) >> 16;
    const int j21 = node - NPG * lg;
    float z[32];
    {
        const int dist = (j21 == 0) ? 0 : (((j21 & 3) == 1) ? j21 : 1);
        const float c = ((j21 & 3) == 1) ? INV_SQRT2 : 0.5f;   // j21==0 -> 0.5, dist 0
        float s0 = 0.f, s1 = 0.f, s2 = 0.f, q0 = 0.f, q1 = 0.f, q2 = 0.f;
        if (node < Mrows) {
            const long long gid = (long long)(g0 + lg) * NPG + j21;
            const float* xp = x + gid * 3;
            s0 = xp[0]; s1 = xp[1]; s2 = xp[2];
            const float* xq = xp - dist * 3;
            q0 = xq[0]; q1 = xq[1]; q2 = xq[2];
        }
        const float ax0 = fmaf(c, q0, 0.5f * s0);
        const float ax1 = fmaf(c, q1, 0.5f * s1);
        const float ax2 = fmaf(c, q2, 0.5f * s2);
        #pragma unroll
        for (int kk = 0; kk < 32; ++kk) {
            const float4 wv = sW1B[k0 + kk];
            float t = fmaf(ax0, wv.x, wv.w);
            t = fmaf(ax1, wv.y, t);
            t = fmaf(ax2, wv.z, t);
            z[kk] = fmaxf(t, 0.f);
        }
        #pragma unroll
        for (int q = 0; q < 8; ++q)
            *(float4*)&sZ[node * 68 + k0 + 4 * q] =
                make_float4(z[4*q], z[4*q+1], z[4*q+2], z[4*q+3]);
    }
    __syncthreads();

    // ---- phase 1.5a: az = A z (in place over z regs) ----
    {
        const int dist = (j21 == 0) ? 0 : (((j21 & 3) == 1) ? j21 : 1);
        const float c = ((j21 & 3) == 1) ? INV_SQRT2 : 0.5f;
        const int prow = node - dist;           // j21==0: self -> az = z
        #pragma unroll
        for (int q = 0; q < 8; ++q) {
            const float4 zp = *(const float4*)&sZ[prow * 68 + k0 + 4 * q];
            z[4*q]   = fmaf(c, zp.x, 0.5f * z[4*q]);
            z[4*q+1] = fmaf(c, zp.y, 0.5f * z[4*q+1]);
            z[4*q+2] = fmaf(c, zp.z, 0.5f * z[4*q+2]);
            z[4*q+3] = fmaf(c, zp.w, 0.5f * z[4*q+3]);
        }
    }
    __syncthreads();                    // all reads done before frag overwrite

    // ---- phase 1.5b: truncate-pack to bf16, write A-frags ----
    {
        unsigned dw[16];
        #pragma unroll
        for (int p = 0; p < 16; ++p)
            dw[p] = __builtin_amdgcn_perm(__float_as_uint(z[2*p+1]),
                                          __float_as_uint(z[2*p]), 0x07060302u);
        char* fragB = (char*)sZ + ((node >> 4) * 2 + s) * 1024 + (node & 15) * 16;
        #pragma unroll
        for (int g = 0; g < 4; ++g)
            *(uint4*)(fragB + g * 256) =
                make_uint4(dw[4*g], dw[4*g+1], dw[4*g+2], dw[4*g+3]);
    }
    __syncthreads();

    // ---- phase 2: MFMA GEMM [128x64]x[64x128] single-pass bf16 + LUT pool ----
    {
        const int w = tid >> 6;
        const int lane = tid & 63;
        const int r = lane & 15;
        const int g4 = lane >> 4;
        const uint4* wsB = (const uint4*)((const unsigned*)ws + WS_BF);
        uint4 B00 = wsB[((2*w+0)*2 + 0)*64 + lane];
        uint4 B01 = wsB[((2*w+0)*2 + 1)*64 + lane];
        uint4 B10 = wsB[((2*w+1)*2 + 0)*64 + lane];
        uint4 B11 = wsB[((2*w+1)*2 + 1)*64 + lane];
        const float b2c0 = sb2[32*w + r];
        const float b2c1 = sb2[32*w + 16 + r];
        const float2* lutp = &sLUT[4 * g4];
        const char* fragB = (const char*)sZ + lane * 16;

        float pg[GPB][2];
        #pragma unroll
        for (int g = 0; g < GPB; ++g) { pg[g][0] = 0.f; pg[g][1] = 0.f; }

        #pragma unroll
        for (int m = 0; m < 8; ++m) {
            const s16x8 A0 = *(const s16x8*)(fragB + (2*m + 0) * 1024);
            const s16x8 A1 = *(const s16x8*)(fragB + (2*m + 1) * 1024);
            f32x4 acc0 = {0.f, 0.f, 0.f, 0.f};
            f32x4 acc1 = {0.f, 0.f, 0.f, 0.f};
            acc0 = __builtin_amdgcn_mfma_f32_16x16x32_bf16(A0, *(const s16x8*)&B00, acc0, 0, 0, 0);
            acc0 = __builtin_amdgcn_mfma_f32_16x16x32_bf16(A1, *(const s16x8*)&B01, acc0, 0, 0, 0);
            acc1 = __builtin_amdgcn_mfma_f32_16x16x32_bf16(A0, *(const s16x8*)&B10, acc1, 0, 0, 0);
            acc1 = __builtin_amdgcn_mfma_f32_16x16x32_bf16(A1, *(const s16x8*)&B11, acc1, 0, 0, 0);

            #pragma unroll
            for (int i = 0; i < 4; ++i) {
                const float2 wg = lutp[16*m + i];          // {wgt, graph}
                const float t0 = fmaxf(acc0[i] + b2c0, 0.f) * wg.x;
                const float t1 = fmaxf(acc1[i] + b2c1, 0.f) * wg.x;
                const int lo = (16*m + i) / 21;            // compile-time
                const int hiRaw = (16*m + i + 12) / 21;    // compile-time
                const int hi = (hiRaw > 5) ? 5 : hiRaw;
                if (lo == hiRaw) {
                    pg[lo][0] += t0; pg[lo][1] += t1;
                } else {
                    const bool cA = (wg.y == (float)lo);
                    const float s0 = cA ? t0 : 0.f;
                    const float s1 = cA ? t1 : 0.f;
                    pg[lo][0] += s0; pg[hi][0] += t0 - s0;
                    pg[lo][1] += s1; pg[hi][1] += t1 - s1;
                }
            }
        }
        // cross-lane reduce over g4 groups (xor 16, 32) and store
        #pragma unroll
        for (int g = 0; g < GPB; ++g) {
            #pragma unroll
            for (int c = 0; c < 2; ++c) {
                float v = pg[g][c];
                v += __shfl_xor(v, 16);
                v += __shfl_xor(v, 32);
                pg[g][c] = v;
            }
        }
        if (lane < 16) {
            #pragma unroll
            for (int g = 0; g < GPB; ++g) {
                sP[g * 128 + 32*w + r]      = pg[g][0];
                sP[g * 128 + 32*w + 16 + r] = pg[g][1];
            }
        }
    }
    __syncthreads();

    // ---- phase 3: logits = sP . W3 + b3 (W3T from global/L2) ; log_softmax ----
    float* sLg = sZ;            // alias (sZ dead)
    float* sRed = sZ + 192;
    if (tid < GPB * NCLS) {
        const int g = (tid * 2260) >> 16;       // /29
        const int c = tid - g * NCLS;
        const float4* w3 = (const float4*)(ws + WS_W3T + c * 128);
        const float4* pp = (const float4*)&sP[g * 128];
        float acc3 = ws[WS_B3 + c];
        #pragma unroll
        for (int k = 0; k < 32; ++k) {
            const float4 wv = w3[k];
            const float4 pv = pp[k];
            acc3 = fmaf(pv.x, wv.x, acc3);
            acc3 = fmaf(pv.y, wv.y, acc3);
            acc3 = fmaf(pv.z, wv.z, acc3);
            acc3 = fmaf(pv.w, wv.w, acc3);
        }
        sLg[tid] = acc3;
    }
    __syncthreads();
    if (tid < nv) {
        float m = -1e30f;
        for (int c = 0; c < NCLS; ++c) m = fmaxf(m, sLg[tid * NCLS + c]);
        float sum = 0.f;
        for (int c = 0; c < NCLS; ++c) sum += expf(sLg[tid * NCLS + c] - m);
        sRed[tid * 2] = m;
        sRed[tid * 2 + 1] = logf(sum);
    }
    __syncthreads();
    if (tid < nv * NCLS) {
        const int g = (tid * 2260) >> 16;
        out[(long long)g0 * NCLS + tid] = sLg[tid] - sRed[g * 2] - sRed[g * 2 + 1];
    }
}

extern "C" void kernel_launch(void* const* d_in, const int* in_sizes, int n_in,
                              void* d_out, int out_size, void* d_ws, size_t ws_size,
                              hipStream_t stream) {
    const float* x   = (const float*)d_in[0];
    const float* W1  = (const float*)d_in[1];
    const float* b1  = (const float*)d_in[2];
    const float* g1  = (const float*)d_in[3];
    const float* be1 = (const float*)d_in[4];
    const float* m1  = (const float*)d_in[5];
    const float* v1  = (const float*)d_in[6];
    const float* W2  = (const float*)d_in[7];
    const float* b2  = (const float*)d_in[8];
    const float* g2  = (const float*)d_in[9];
    const float* be2 = (const float*)d_in[10];
    const float* m2  = (const float*)d_in[11];
    const float* v2  = (const float*)d_in[12];
    const float* W3  = (const float*)d_in[13];
    const float* b3  = (const float*)d_in[14];
    float* out = (float*)d_out;
    float* ws  = (float*)d_ws;

    prep_kernel<<<(WS_TOTAL + 255) / 256, 256, 0, stream>>>(
        W1, b1, g1, be1, m1, v1, W2, b2, g2, be2, m2, v2, W3, b3, ws);

    gcn_main<<<NCHUNK, 256, 0, stream>>>(x, ws, out);
}

// Round 5
// 200.919 us; speedup vs baseline: 1.0981x; 1.0981x over previous
//
#include <hip/hip_runtime.h>
#include <math.h>

// GCN on 50000 disjoint 21-node hand-skeleton graphs (fixed topology).
// Fused: aggregate-before-matmul, BN folded into W/b, pooling commuted past W3.
// R5: bf16 frag-layout staging only (22KB LDS -> 7 blk/CU), parent exchange in
// bf16, coalesced x staging via LDS, wave-parallel softmax, 1-pass bf16 MFMA.

#define G_TOTAL 50000
#define NPG 21
#define GPB 6
#define NCHUNK ((G_TOTAL + GPB - 1) / GPB)     // 8334
#define NCLS 29
#define BN_EPS 1e-5f
#define INV_SQRT2 0.70710678118654752440f
#define ROOT_COLSUM 4.53553390593273762f       // 1 + 5/sqrt(2)

// ws dword layout
#define WS_W1B  0              // 256: [k]{w0,w1,w2,b1f} float4-interleaved
#define WS_B2   256            // 128
#define WS_B3   384            // 32 (29 used)
#define WS_W3T  416            // 3712: W3T [29][128]
#define WS_BF   4128           // 4096: W2 B-frags, bf16 RNE, [n8][ss2][lane64][4dw]
#define WS_TOTAL (WS_BF + 4096)

typedef short s16x8 __attribute__((ext_vector_type(8)));
typedef float f32x4 __attribute__((ext_vector_type(4)));

__device__ __forceinline__ unsigned f2bf_rne(float f) {
    unsigned u = __float_as_uint(f);
    return (u + 0x7FFFu + ((u >> 16) & 1u)) >> 16;
}

__global__ void prep_kernel(const float* __restrict__ W1, const float* __restrict__ b1,
                            const float* __restrict__ g1, const float* __restrict__ be1,
                            const float* __restrict__ m1, const float* __restrict__ v1,
                            const float* __restrict__ W2, const float* __restrict__ b2,
                            const float* __restrict__ g2, const float* __restrict__ be2,
                            const float* __restrict__ m2, const float* __restrict__ v2,
                            const float* __restrict__ W3, const float* __restrict__ b3,
                            float* __restrict__ ws) {
    int t = blockIdx.x * blockDim.x + threadIdx.x;
    if (t < 256) {                              // W1B interleave
        int k = t >> 2, comp = t & 3;
        float s = g1[k] * rsqrtf(v1[k] + BN_EPS);
        float v;
        if (comp < 3) v = W1[comp * 64 + k] * s;
        else          v = (b1[k] - m1[k]) * s + be1[k];
        ws[WS_W1B + t] = v;
    } else if (t < 384) {                       // b2f
        int j = t - 256;
        float s = g2[j] * rsqrtf(v2[j] + BN_EPS);
        ws[WS_B2 + j] = (b2[j] - m2[j]) * s + be2[j];
    } else if (t < 416) {                       // b3 (pad 32)
        int j = t - 384;
        ws[WS_B3 + j] = (j < NCLS) ? b3[j] : 0.f;
    } else if (t < WS_BF) {                     // W3T[c][k] = W3[k*29+c]
        int i = t - WS_W3T;
        if (i < 3712) {
            int c = i >> 7, k = i & 127;
            ws[WS_W3T + i] = W3[k * NCLS + c];
        }
    } else if (t < WS_TOTAL) {                  // B-frags of W2f (bf16 RNE)
        int i = t - WS_BF;                      // dword index
        int d  = i & 3;
        int l  = (i >> 2) & 63;
        int ss = (i >> 8) & 1;
        int n  = i >> 9;                        // 0..7
        int kg = l >> 4, r = l & 15;
        int c = 16 * n + r;
        float sc = g2[c] * rsqrtf(v2[c] + BN_EPS);
        int k0 = 32 * ss + 8 * kg + 2 * d;
        unsigned h0 = f2bf_rne(W2[k0 * 128 + c] * sc);
        unsigned h1 = f2bf_rne(W2[(k0 + 1) * 128 + c] * sc);
        ((unsigned*)ws)[WS_BF + i] = (h1 << 16) | h0;
    }
}

__global__ __launch_bounds__(256, 7)
void gcn_main(const float* __restrict__ x, const float* __restrict__ ws,
              float* __restrict__ out) {
    // sFrag: A-fragment buffer (bf16 z / az), 16 KB; phase3 alias: sLg[174]
    __shared__ __align__(16) float sFrag[4096];
    __shared__ __align__(16) float4 sW1B[64];
    __shared__ float sb2[128];
    __shared__ __align__(8) float2 sLUT[128];
    __shared__ __align__(16) float sP[GPB * 128];   // aliases sX staging (<=378 fl)

    const int tid = threadIdx.x;
    const int g0 = blockIdx.x * GPB;
    const int nv = min(GPB, G_TOTAL - g0);
    const int Mrows = nv * NPG;

    // ---- stage weights, row LUT, and x slice (coalesced float2) ----
    if (tid < 64) sW1B[tid] = ((const float4*)ws)[tid];
    else if (tid < 192) sb2[tid - 64] = ws[WS_B2 + (tid - 64)];
    if (tid < 128) {
        const int r = tid;
        const int lg2 = (r * 3121) >> 16;       // r/21
        const int j = r - NPG * lg2;
        float w = (j == 0) ? (ROOT_COLSUM / 21.f)
                           : (((j & 3) == 0) ? (0.5f / 21.f) : (1.f / 21.f));
        if (r >= Mrows) w = 0.f;
        sLUT[r] = make_float2(w, (float)lg2);
    }
    {
        const int n2 = (Mrows * 3) >> 1;        // <=189 float2
        const float2* xg2 = (const float2*)(x + (long long)g0 * 63);
        if (tid < n2) ((float2*)sP)[tid] = xg2[tid];
    }
    __syncthreads();

    // ---- phase 1: z[node][k] = relu((A x)[node].W1f + b1f), pack bf16 frags ----
    const int node = tid >> 1;          // 0..127
    const int s = tid & 1;
    const int k0 = s * 32;
    const int lg = (node * 3121) >> 16;
    const int j21 = node - NPG * lg;
    const int dist = (j21 == 0) ? 0 : (((j21 & 3) == 1) ? j21 : 1);
    const float cw = ((j21 & 3) == 1) ? INV_SQRT2 : 0.5f;
    char* const fragB = (char*)sFrag + ((node >> 4) * 2 + s) * 1024 + (node & 15) * 16;
    float z[32];
    {
        const float* xs = (const float*)sP + node * 3;
        const float s0 = xs[0], s1 = xs[1], s2 = xs[2];
        const float* xq = xs - dist * 3;
        const float ax0 = fmaf(cw, xq[0], 0.5f * s0);
        const float ax1 = fmaf(cw, xq[1], 0.5f * s1);
        const float ax2 = fmaf(cw, xq[2], 0.5f * s2);
        #pragma unroll
        for (int kk = 0; kk < 32; ++kk) {
            const float4 wv = sW1B[k0 + kk];
            float t = fmaf(ax0, wv.x, wv.w);
            t = fmaf(ax1, wv.y, t);
            t = fmaf(ax2, wv.z, t);
            z[kk] = fmaxf(t, 0.f);
        }
        unsigned dw[16];
        #pragma unroll
        for (int p = 0; p < 16; ++p)
            dw[p] = __builtin_amdgcn_perm(__float_as_uint(z[2*p+1]),
                                          __float_as_uint(z[2*p]), 0x07060302u);
        #pragma unroll
        for (int g = 0; g < 4; ++g)
            *(uint4*)(fragB + g * 256) =
                make_uint4(dw[4*g], dw[4*g+1], dw[4*g+2], dw[4*g+3]);
    }
    __syncthreads();

    // ---- phase 1.5a: az = c*z[parent](bf16) + 0.5*z[self](fp32 regs) ----
    if (dist != 0) {
        const int prow = node - dist;
        const char* pfrag = (const char*)sFrag
                          + ((prow >> 4) * 2 + s) * 1024 + (prow & 15) * 16;
        #pragma unroll
        for (int g = 0; g < 4; ++g) {
            const uint4 pd = *(const uint4*)(pfrag + g * 256);
            const unsigned d4[4] = {pd.x, pd.y, pd.z, pd.w};
            #pragma unroll
            for (int d = 0; d < 4; ++d) {
                const float plo = __uint_as_float(d4[d] << 16);
                const float phi = __uint_as_float(d4[d] & 0xFFFF0000u);
                z[8*g + 2*d]     = fmaf(cw, plo, 0.5f * z[8*g + 2*d]);
                z[8*g + 2*d + 1] = fmaf(cw, phi, 0.5f * z[8*g + 2*d + 1]);
            }
        }
    }
    __syncthreads();                    // all parent reads done before overwrite

    // ---- phase 1.5b: repack az to frags (in place) ----
    {
        unsigned dw[16];
        #pragma unroll
        for (int p = 0; p < 16; ++p)
            dw[p] = __builtin_amdgcn_perm(__float_as_uint(z[2*p+1]),
                                          __float_as_uint(z[2*p]), 0x07060302u);
        #pragma unroll
        for (int g = 0; g < 4; ++g)
            *(uint4*)(fragB + g * 256) =
                make_uint4(dw[4*g], dw[4*g+1], dw[4*g+2], dw[4*g+3]);
    }
    __syncthreads();

    // ---- phase 2: MFMA GEMM [128x64]x[64x128] single-pass bf16 + LUT pool ----
    {
        const int w = tid >> 6;
        const int lane = tid & 63;
        const int r = lane & 15;
        const int g4 = lane >> 4;
        const uint4* wsB = (const uint4*)((const unsigned*)ws + WS_BF);
        uint4 B00 = wsB[((2*w+0)*2 + 0)*64 + lane];
        uint4 B01 = wsB[((2*w+0)*2 + 1)*64 + lane];
        uint4 B10 = wsB[((2*w+1)*2 + 0)*64 + lane];
        uint4 B11 = wsB[((2*w+1)*2 + 1)*64 + lane];
        const float b2c0 = sb2[32*w + r];
        const float b2c1 = sb2[32*w + 16 + r];
        const float2* lutp = &sLUT[4 * g4];
        const char* fragA = (const char*)sFrag + lane * 16;

        float pg[GPB][2];
        #pragma unroll
        for (int g = 0; g < GPB; ++g) { pg[g][0] = 0.f; pg[g][1] = 0.f; }

        #pragma unroll
        for (int m = 0; m < 8; ++m) {
            const s16x8 A0 = *(const s16x8*)(fragA + (2*m + 0) * 1024);
            const s16x8 A1 = *(const s16x8*)(fragA + (2*m + 1) * 1024);
            f32x4 acc0 = {0.f, 0.f, 0.f, 0.f};
            f32x4 acc1 = {0.f, 0.f, 0.f, 0.f};
            acc0 = __builtin_amdgcn_mfma_f32_16x16x32_bf16(A0, *(const s16x8*)&B00, acc0, 0, 0, 0);
            acc0 = __builtin_amdgcn_mfma_f32_16x16x32_bf16(A1, *(const s16x8*)&B01, acc0, 0, 0, 0);
            acc1 = __builtin_amdgcn_mfma_f32_16x16x32_bf16(A0, *(const s16x8*)&B10, acc1, 0, 0, 0);
            acc1 = __builtin_amdgcn_mfma_f32_16x16x32_bf16(A1, *(const s16x8*)&B11, acc1, 0, 0, 0);

            #pragma unroll
            for (int i = 0; i < 4; ++i) {
                const float2 wg = lutp[16*m + i];          // {wgt, graph}
                const float t0 = fmaxf(acc0[i] + b2c0, 0.f) * wg.x;
                const float t1 = fmaxf(acc1[i] + b2c1, 0.f) * wg.x;
                const int lo = (16*m + i) / 21;            // compile-time
                const int hiRaw = (16*m + i + 12) / 21;    // compile-time
                const int hi = (hiRaw > 5) ? 5 : hiRaw;
                if (lo == hiRaw) {
                    pg[lo][0] += t0; pg[lo][1] += t1;
                } else {
                    const bool cA = (wg.y == (float)lo);
                    const float s0 = cA ? t0 : 0.f;
                    const float s1 = cA ? t1 : 0.f;
                    pg[lo][0] += s0; pg[hi][0] += t0 - s0;
                    pg[lo][1] += s1; pg[hi][1] += t1 - s1;
                }
            }
        }
        #pragma unroll
        for (int g = 0; g < GPB; ++g) {
            #pragma unroll
            for (int c = 0; c < 2; ++c) {
                float v = pg[g][c];
                v += __shfl_xor(v, 16);
                v += __shfl_xor(v, 32);
                pg[g][c] = v;
            }
        }
        if (lane < 16) {
            #pragma unroll
            for (int g = 0; g < GPB; ++g) {
                sP[g * 128 + 32*w + r]      = pg[g][0];
                sP[g * 128 + 32*w + 16 + r] = pg[g][1];
            }
        }
    }
    __syncthreads();

    // ---- phase 3: logits = sP . W3 + b3 (W3T from global/L2) ----
    float* sLg = sFrag;                 // alias (frags dead)
    if (tid < GPB * NCLS) {
        const int g = (tid * 2260) >> 16;       // /29
        const int c = tid - g * NCLS;
        const float4* w3 = (const float4*)(ws + WS_W3T + c * 128);
        const float4* pp = (const float4*)&sP[g * 128];
        float acc3 = ws[WS_B3 + c];
        #pragma unroll
        for (int k = 0; k < 32; ++k) {
            const float4 wv = w3[k];
            const float4 pv = pp[k];
            acc3 = fmaf(pv.x, wv.x, acc3);
            acc3 = fmaf(pv.y, wv.y, acc3);
            acc3 = fmaf(pv.z, wv.z, acc3);
            acc3 = fmaf(pv.w, wv.w, acc3);
        }
        sLg[tid] = acc3;
    }
    __syncthreads();

    // ---- wave-parallel log_softmax: 6 groups x 32 lanes ----
    if (tid < 192) {
        const int g = tid >> 5, c = tid & 31;
        const bool act = (c < NCLS) && (g < nv);
        float v = act ? sLg[g * NCLS + c] : -1e30f;
        float m = v;
        m = fmaxf(m, __shfl_xor(m, 1));
        m = fmaxf(m, __shfl_xor(m, 2));
        m = fmaxf(m, __shfl_xor(m, 4));
        m = fmaxf(m, __shfl_xor(m, 8));
        m = fmaxf(m, __shfl_xor(m, 16));
        float e = act ? expf(v - m) : 0.f;
        float ss = e;
        ss += __shfl_xor(ss, 1);
        ss += __shfl_xor(ss, 2);
        ss += __shfl_xor(ss, 4);
        ss += __shfl_xor(ss, 8);
        ss += __shfl_xor(ss, 16);
        if (act)
            out[(long long)g0 * NCLS + g * NCLS + c] = v - m - logf(ss);
    }
}

extern "C" void kernel_launch(void* const* d_in, const int* in_sizes, int n_in,
                              void* d_out, int out_size, void* d_ws, size_t ws_size,
                              hipStream_t stream) {
    const float* x   = (const float*)d_in[0];
    const float* W1  = (const float*)d_in[1];
    const float* b1  = (const float*)d_in[2];
    const float* g1  = (const float*)d_in[3];
    const float* be1 = (const float*)d_in[4];
    const float* m1  = (const float*)d_in[5];
    const float* v1  = (const float*)d_in[6];
    const float* W2  = (const float*)d_in[7];
    const float* b2  = (const float*)d_in[8];
    const float* g2  = (const float*)d_in[9];
    const float* be2 = (const float*)d_in[10];
    const float* m2  = (const float*)d_in[11];
    const float* v2  = (const float*)d_in[12];
    const float* W3  = (const float*)d_in[13];
    const float* b3  = (const float*)d_in[14];
    float* out = (float*)d_out;
    float* ws  = (float*)d_ws;

    prep_kernel<<<(WS_TOTAL + 255) / 256, 256, 0, stream>>>(
        W1, b1, g1, be1, m1, v1, W2, b2, g2, be2, m2, v2, W3, b3, ws);

    gcn_main<<<NCHUNK, 256, 0, stream>>>(x, ws, out);
}

// Round 6
// 196.027 us; speedup vs baseline: 1.1255x; 1.0250x over previous
//
#include <hip/hip_runtime.h>
#include <math.h>

// GCN on 50000 disjoint 21-node hand-skeleton graphs (fixed topology).
// Fused: aggregate-before-matmul, BN folded into W/b, pooling commuted past W3.
// R6: GPB=4 (no tail), graph-per-lane-group frag ordering -> literal pool
// weights + zero-shuffle epilogue; in-loop parent-z (phases 1.5 deleted, 4
// barriers total); 15.7KB LDS -> 8 blocks/CU; b2/b3 from L2; __expf/__logf.

#define G_TOTAL 50000
#define GPB 4
#define NBLK (G_TOTAL / GPB)               // 12500, exact
#define NCLS 29
#define BN_EPS 1e-5f
#define INV_SQRT2 0.70710678118654752440f
#define ROOT_W 0.21597780504441608f        // (1 + 5/sqrt(2)) / 21

// ws dword layout (unchanged from R5)
#define WS_W1B  0              // 256: [k]{w0,w1,w2,b1f} float4-interleaved
#define WS_B2   256            // 128
#define WS_B3   384            // 32 (29 used)
#define WS_W3T  416            // 3712: W3T [29][128]
#define WS_BF   4128           // 4096: W2 B-frags, bf16 RNE, [n8][ss2][lane64][4dw]
#define WS_TOTAL (WS_BF + 4096)

#define TSTRIDE 1056           // frag tile stride (1024 + 32 pad: de-conflicts writes)

typedef short s16x8 __attribute__((ext_vector_type(8)));
typedef float f32x4 __attribute__((ext_vector_type(4)));

__device__ __forceinline__ unsigned f2bf_rne(float f) {
    unsigned u = __float_as_uint(f);
    return (u + 0x7FFFu + ((u >> 16) & 1u)) >> 16;
}

__global__ void prep_kernel(const float* __restrict__ W1, const float* __restrict__ b1,
                            const float* __restrict__ g1, const float* __restrict__ be1,
                            const float* __restrict__ m1, const float* __restrict__ v1,
                            const float* __restrict__ W2, const float* __restrict__ b2,
                            const float* __restrict__ g2, const float* __restrict__ be2,
                            const float* __restrict__ m2, const float* __restrict__ v2,
                            const float* __restrict__ W3, const float* __restrict__ b3,
                            float* __restrict__ ws) {
    int t = blockIdx.x * blockDim.x + threadIdx.x;
    if (t < 256) {                              // W1B interleave
        int k = t >> 2, comp = t & 3;
        float s = g1[k] * rsqrtf(v1[k] + BN_EPS);
        float v;
        if (comp < 3) v = W1[comp * 64 + k] * s;
        else          v = (b1[k] - m1[k]) * s + be1[k];
        ws[WS_W1B + t] = v;
    } else if (t < 384) {                       // b2f
        int j = t - 256;
        float s = g2[j] * rsqrtf(v2[j] + BN_EPS);
        ws[WS_B2 + j] = (b2[j] - m2[j]) * s + be2[j];
    } else if (t < 416) {                       // b3 (pad 32)
        int j = t - 384;
        ws[WS_B3 + j] = (j < NCLS) ? b3[j] : 0.f;
    } else if (t < WS_BF) {                     // W3T[c][k] = W3[k*29+c]
        int i = t - WS_W3T;
        if (i < 3712) {
            int c = i >> 7, k = i & 127;
            ws[WS_W3T + i] = W3[k * NCLS + c];
        }
    } else if (t < WS_TOTAL) {                  // B-frags of W2f (bf16 RNE)
        int i = t - WS_BF;                      // dword index
        int d  = i & 3;
        int l  = (i >> 2) & 63;
        int ss = (i >> 8) & 1;
        int n  = i >> 9;                        // 0..7
        int kg = l >> 4, r = l & 15;
        int c = 16 * n + r;
        float sc = g2[c] * rsqrtf(v2[c] + BN_EPS);
        int k0 = 32 * ss + 8 * kg + 2 * d;
        unsigned h0 = f2bf_rne(W2[k0 * 128 + c] * sc);
        unsigned h1 = f2bf_rne(W2[(k0 + 1) * 128 + c] * sc);
        ((unsigned*)ws)[WS_BF + i] = (h1 << 16) | h0;
    }
}

__global__ __launch_bounds__(256, 8)
void gcn_main(const float* __restrict__ x, const float* __restrict__ ws,
              float* __restrict__ out) {
    // sFrag: az bf16 A-frags, 12 tiles x TSTRIDE; phase3 alias: sLg[116]
    __shared__ __align__(16) char sFrag[12 * TSTRIDE];     // 12672 B
    __shared__ __align__(16) float4 sW1B[64];              // 1 KB
    __shared__ __align__(16) float sPX[512];               // x-stage (252) then pooled[4][128]

    const int tid = threadIdx.x;
    const long long blk = blockIdx.x;

    // ---- stage: W1B, x slice (63 float4, coalesced), zero m=5 pad tiles ----
    if (tid < 64) sW1B[tid] = ((const float4*)ws)[tid];
    if (tid < 63) ((float4*)sPX)[tid] = ((const float4*)(x + blk * 252))[tid];
    if (tid >= 64 && tid < 64 + 132)
        *(float4*)(sFrag + 10 * TSTRIDE + (tid - 64) * 16) =
            make_float4(0.f, 0.f, 0.f, 0.f);
    __syncthreads();

    // ---- phase 1: az[node][k] computed directly (self + parent z in-loop),
    //      packed bf16 into A-frags. frag row (tile m=p>>2) = 4*g + (p&3). ----
    if (tid < 168) {
        const int node = tid >> 1;          // 0..83
        const int s = tid & 1;
        const int k0 = s * 32;
        const int g4 = (node * 3121) >> 16; // node/21
        const int p  = node - 21 * g4;      // node index within graph
        const int dist  = (p == 0) ? 0 : (((p & 3) == 1) ? p : 1);
        const float cw  = ((p & 3) == 1) ? INV_SQRT2 : 0.5f;
        const int jp = p - dist;            // parent's j
        const int dist2 = (jp == 0) ? 0 : (((jp & 3) == 1) ? jp : 1);
        const float cw2 = ((jp & 3) == 1) ? INV_SQRT2 : 0.5f;

        const float* xs = (const float*)sPX + node * 3;
        const float* xq = xs - dist * 3;    // parent x
        const float* xg = xq - dist2 * 3;   // grandparent x
        const float ax0 = fmaf(cw,  xq[0], 0.5f * xs[0]);   // (A x)[self]
        const float ax1 = fmaf(cw,  xq[1], 0.5f * xs[1]);
        const float ax2 = fmaf(cw,  xq[2], 0.5f * xs[2]);
        const float bx0 = fmaf(cw2, xg[0], 0.5f * xq[0]);   // (A x)[parent]
        const float bx1 = fmaf(cw2, xg[1], 0.5f * xq[1]);
        const float bx2 = fmaf(cw2, xg[2], 0.5f * xq[2]);

        float az[32];
        #pragma unroll
        for (int kk = 0; kk < 32; ++kk) {
            const float4 wv = sW1B[k0 + kk];
            float ts = fmaf(ax0, wv.x, wv.w);
            ts = fmaf(ax1, wv.y, ts);
            ts = fmaf(ax2, wv.z, ts);
            ts = fmaxf(ts, 0.f);                    // z[self]
            float tp = fmaf(bx0, wv.x, wv.w);
            tp = fmaf(bx1, wv.y, tp);
            tp = fmaf(bx2, wv.z, tp);
            tp = fmaxf(tp, 0.f);                    // z[parent] (== z[self] if root)
            az[kk] = fmaf(cw, tp, 0.5f * ts);       // root: 0.5+0.5 = 1.0 * z
        }
        unsigned dw[16];
        #pragma unroll
        for (int q = 0; q < 16; ++q)
            dw[q] = __builtin_amdgcn_perm(__float_as_uint(az[2*q+1]),
                                          __float_as_uint(az[2*q]), 0x07060302u);
        char* fragB = sFrag + ((p >> 2) * 2 + s) * TSTRIDE + (4 * g4 + (p & 3)) * 16;
        #pragma unroll
        for (int kg = 0; kg < 4; ++kg)
            *(uint4*)(fragB + kg * 256) =
                make_uint4(dw[4*kg], dw[4*kg+1], dw[4*kg+2], dw[4*kg+3]);
    }
    __syncthreads();

    // ---- phase 2: MFMA GEMM [96x64]x[64x128] + literal-weight pool ----
    {
        const int w = tid >> 6;
        const int lane = tid & 63;
        const int r = lane & 15;
        const int lg = lane >> 4;           // this lane-group's graph
        const uint4* wsB = (const uint4*)((const unsigned*)ws + WS_BF);
        const uint4 B00 = wsB[((2*w+0)*2 + 0)*64 + lane];
        const uint4 B01 = wsB[((2*w+0)*2 + 1)*64 + lane];
        const uint4 B10 = wsB[((2*w+1)*2 + 0)*64 + lane];
        const uint4 B11 = wsB[((2*w+1)*2 + 1)*64 + lane];
        const float b2c0 = ws[WS_B2 + 32*w + r];
        const float b2c1 = ws[WS_B2 + 32*w + 16 + r];
        const char* fragA = sFrag + lane * 16;

        float pg0 = 0.f, pg1 = 0.f;
        #pragma unroll
        for (int m = 0; m < 6; ++m) {
            const s16x8 A0 = *(const s16x8*)(fragA + (2*m + 0) * TSTRIDE);
            const s16x8 A1 = *(const s16x8*)(fragA + (2*m + 1) * TSTRIDE);
            f32x4 acc0 = {0.f, 0.f, 0.f, 0.f};
            f32x4 acc1 = {0.f, 0.f, 0.f, 0.f};
            acc0 = __builtin_amdgcn_mfma_f32_16x16x32_bf16(A0, *(const s16x8*)&B00, acc0, 0, 0, 0);
            acc0 = __builtin_amdgcn_mfma_f32_16x16x32_bf16(A1, *(const s16x8*)&B01, acc0, 0, 0, 0);
            acc1 = __builtin_amdgcn_mfma_f32_16x16x32_bf16(A0, *(const s16x8*)&B10, acc1, 0, 0, 0);
            acc1 = __builtin_amdgcn_mfma_f32_16x16x32_bf16(A1, *(const s16x8*)&B11, acc1, 0, 0, 0);

            #pragma unroll
            for (int i = 0; i < 4; ++i) {
                const int p = 4*m + i;              // node index within graph
                if (p < 21) {
                    const float wgt = (p == 0) ? ROOT_W
                                    : (((p & 3) == 0) ? (0.5f / 21.f) : (1.f / 21.f));
                    pg0 = fmaf(wgt, fmaxf(acc0[i] + b2c0, 0.f), pg0);
                    pg1 = fmaf(wgt, fmaxf(acc1[i] + b2c1, 0.f), pg1);
                }
            }
        }
        // bijective (graph, col) -> lane: direct store, no reduction
        sPX[lg * 128 + 32*w + r]      = pg0;
        sPX[lg * 128 + 32*w + 16 + r] = pg1;
    }
    __syncthreads();

    // ---- phase 3: logits = pooled . W3 + b3 (W3T from L2) ----
    float* sLg = (float*)sFrag;                 // alias (frags dead)
    if (tid < GPB * NCLS) {                     // 116 threads
        const int g = (tid * 2260) >> 16;       // /29
        const int c = tid - g * NCLS;
        const float4* w3 = (const float4*)(ws + WS_W3T + c * 128);
        const float4* pp = (const float4*)&sPX[g * 128];
        float acc3 = ws[WS_B3 + c];
        #pragma unroll
        for (int k = 0; k < 32; ++k) {
            const float4 wv = w3[k];
            const float4 pv = pp[k];
            acc3 = fmaf(pv.x, wv.x, acc3);
            acc3 = fmaf(pv.y, wv.y, acc3);
            acc3 = fmaf(pv.z, wv.z, acc3);
            acc3 = fmaf(pv.w, wv.w, acc3);
        }
        sLg[tid] = acc3;
    }
    __syncthreads();

    // ---- wave-parallel log_softmax: 4 groups x 32 lanes ----
    if (tid < 128) {
        const int g = tid >> 5, c = tid & 31;
        const bool act = (c < NCLS);
        float v = act ? sLg[g * NCLS + c] : -1e30f;
        float m = v;
        m = fmaxf(m, __shfl_xor(m, 1));
        m = fmaxf(m, __shfl_xor(m, 2));
        m = fmaxf(m, __shfl_xor(m, 4));
        m = fmaxf(m, __shfl_xor(m, 8));
        m = fmaxf(m, __shfl_xor(m, 16));
        float e = act ? __expf(v - m) : 0.f;
        float ss = e;
        ss += __shfl_xor(ss, 1);
        ss += __shfl_xor(ss, 2);
        ss += __shfl_xor(ss, 4);
        ss += __shfl_xor(ss, 8);
        ss += __shfl_xor(ss, 16);
        if (act)
            out[blk * (GPB * NCLS) + g * NCLS + c] = v - m - __logf(ss);
    }
}

extern "C" void kernel_launch(void* const* d_in, const int* in_sizes, int n_in,
                              void* d_out, int out_size, void* d_ws, size_t ws_size,
                              hipStream_t stream) {
    const float* x   = (const float*)d_in[0];
    const float* W1  = (const float*)d_in[1];
    const float* b1  = (const float*)d_in[2];
    const float* g1  = (const float*)d_in[3];
    const float* be1 = (const float*)d_in[4];
    const float* m1  = (const float*)d_in[5];
    const float* v1  = (const float*)d_in[6];
    const float* W2  = (const float*)d_in[7];
    const float* b2  = (const float*)d_in[8];
    const float* g2  = (const float*)d_in[9];
    const float* be2 = (const float*)d_in[10];
    const float* m2  = (const float*)d_in[11];
    const float* v2  = (const float*)d_in[12];
    const float* W3  = (const float*)d_in[13];
    const float* b3  = (const float*)d_in[14];
    float* out = (float*)d_out;
    float* ws  = (float*)d_ws;

    prep_kernel<<<(WS_TOTAL + 255) / 256, 256, 0, stream>>>(
        W1, b1, g1, be1, m1, v1, W2, b2, g2, be2, m2, v2, W3, b3, ws);

    gcn_main<<<NBLK, 256, 0, stream>>>(x, ws, out);
}

// Round 7
// 187.626 us; speedup vs baseline: 1.1759x; 1.0448x over previous
//
#include <hip/hip_runtime.h>
#include <math.h>

// GCN on 50000 disjoint 21-node hand-skeleton graphs (fixed topology).
// Fused: aggregate-before-matmul, BN folded into W/b, pooling commuted past W3.
// R7: persistent pipelined blocks (2500 x 5 chunks): ph1[next] (VALU) overlaps
// ph2[cur] (MFMA) in one barrier interval; double-buffered frags + x prefetch;
// barrier-free phase 3 (graph-per-wave, 2-way LDS reads, shfl softmax);
// weights/B-frags hoisted into registers across chunks. 2 barriers/chunk.

#define G_TOTAL 50000
#define GPB 4
#define CPB 5                               // chunks per block
#define NBLK (G_TOTAL / (GPB * CPB))        // 2500, exact
#define NCLS 29
#define BN_EPS 1e-5f
#define INV_SQRT2 0.70710678118654752440f
#define ROOT_W 0.21597780504441608f         // (1 + 5/sqrt(2)) / 21

// ws dword layout (unchanged)
#define WS_W1B  0              // 256: [k]{w0,w1,w2,b1f} float4-interleaved
#define WS_B2   256            // 128
#define WS_B3   384            // 32 (29 used)
#define WS_W3T  416            // 3712: W3T [29][128]
#define WS_BF   4128           // 4096: W2 B-frags bf16 [n8][ss2][lane64][4dw]
#define WS_TOTAL (WS_BF + 4096)

#define TSTRIDE 1056           // frag tile stride (1024 + 32 pad)
#define FRAGBUF (12 * TSTRIDE) // 12672 B per buffer

typedef short s16x8 __attribute__((ext_vector_type(8)));
typedef float f32x4 __attribute__((ext_vector_type(4)));

__device__ __forceinline__ unsigned f2bf_rne(float f) {
    unsigned u = __float_as_uint(f);
    return (u + 0x7FFFu + ((u >> 16) & 1u)) >> 16;
}

__global__ void prep_kernel(const float* __restrict__ W1, const float* __restrict__ b1,
                            const float* __restrict__ g1, const float* __restrict__ be1,
                            const float* __restrict__ m1, const float* __restrict__ v1,
                            const float* __restrict__ W2, const float* __restrict__ b2,
                            const float* __restrict__ g2, const float* __restrict__ be2,
                            const float* __restrict__ m2, const float* __restrict__ v2,
                            const float* __restrict__ W3, const float* __restrict__ b3,
                            float* __restrict__ ws) {
    int t = blockIdx.x * blockDim.x + threadIdx.x;
    if (t < 256) {                              // W1B interleave
        int k = t >> 2, comp = t & 3;
        float s = g1[k] * rsqrtf(v1[k] + BN_EPS);
        float v;
        if (comp < 3) v = W1[comp * 64 + k] * s;
        else          v = (b1[k] - m1[k]) * s + be1[k];
        ws[WS_W1B + t] = v;
    } else if (t < 384) {                       // b2f
        int j = t - 256;
        float s = g2[j] * rsqrtf(v2[j] + BN_EPS);
        ws[WS_B2 + j] = (b2[j] - m2[j]) * s + be2[j];
    } else if (t < 416) {                       // b3 (pad 32)
        int j = t - 384;
        ws[WS_B3 + j] = (j < NCLS) ? b3[j] : 0.f;
    } else if (t < WS_BF) {                     // W3T[c][k] = W3[k*29+c]
        int i = t - WS_W3T;
        if (i < 3712) {
            int c = i >> 7, k = i & 127;
            ws[WS_W3T + i] = W3[k * NCLS + c];
        }
    } else if (t < WS_TOTAL) {                  // B-frags of W2f (bf16 RNE)
        int i = t - WS_BF;                      // dword index
        int d  = i & 3;
        int l  = (i >> 2) & 63;
        int ss = (i >> 8) & 1;
        int n  = i >> 9;                        // 0..7
        int kg = l >> 4, r = l & 15;
        int c = 16 * n + r;
        float sc = g2[c] * rsqrtf(v2[c] + BN_EPS);
        int k0 = 32 * ss + 8 * kg + 2 * d;
        unsigned h0 = f2bf_rne(W2[k0 * 128 + c] * sc);
        unsigned h1 = f2bf_rne(W2[(k0 + 1) * 128 + c] * sc);
        ((unsigned*)ws)[WS_BF + i] = (h1 << 16) | h0;
    }
}

__global__ __launch_bounds__(256, 4)
void gcn_main(const float* __restrict__ x, const float* __restrict__ ws,
              float* __restrict__ out) {
    __shared__ __align__(16) char sFrag[2][FRAGBUF];   // 25344 B
    __shared__ __align__(16) float4 sW1B[64];          // 1 KB
    __shared__ __align__(16) float4 sX[2][64];         // 2 KB (63 used per buf)
    __shared__ __align__(16) float sPool[4 * 132];     // padded stride 132

    const int tid = threadIdx.x;
    const int lane = tid & 63;
    const int w = tid >> 6;
    const int r = lane & 15;
    const int lg = lane >> 4;
    const long long cbase = (long long)blockIdx.x * CPB;

    // ---- per-thread constants held across all chunks ----
    const uint4* wsB = (const uint4*)((const unsigned*)ws + WS_BF);
    const uint4 B00 = wsB[((2*w+0)*2 + 0)*64 + lane];
    const uint4 B01 = wsB[((2*w+0)*2 + 1)*64 + lane];
    const uint4 B10 = wsB[((2*w+1)*2 + 0)*64 + lane];
    const uint4 B11 = wsB[((2*w+1)*2 + 1)*64 + lane];
    const float b2c0 = ws[WS_B2 + 32*w + r];
    const float b2c1 = ws[WS_B2 + 32*w + 16 + r];
    const int cc = lane >> 1;               // phase-3 class (lane<58)
    const int h3 = lane & 1;                // phase-3 k-half
    const float b3r = ws[WS_B3 + (cc < NCLS ? cc : 0)];
    const float* w3base = ws + WS_W3T + cc * 128 + 64 * h3;

    // ---- phase-1 helper: az for chunk whose x is in sX[buf] -> sFrag[buf] ----
    auto phase1 = [&](int buf) {
        if (tid < 168) {
            const int node = tid >> 1;
            const int s = tid & 1;
            const int k0q = s * 32;
            const int g4 = (node * 3121) >> 16;     // node/21
            const int p  = node - 21 * g4;
            const int dist  = (p == 0) ? 0 : (((p & 3) == 1) ? p : 1);
            const float cw  = ((p & 3) == 1) ? INV_SQRT2 : 0.5f;
            const int jp = p - dist;
            const int dist2 = (jp == 0) ? 0 : (((jp & 3) == 1) ? jp : 1);
            const float cw2 = ((jp & 3) == 1) ? INV_SQRT2 : 0.5f;
            const float* xs = (const float*)&sX[buf][0] + node * 3;
            const float* xq = xs - dist * 3;
            const float* xg = xq - dist2 * 3;
            const float ax0 = fmaf(cw,  xq[0], 0.5f * xs[0]);
            const float ax1 = fmaf(cw,  xq[1], 0.5f * xs[1]);
            const float ax2 = fmaf(cw,  xq[2], 0.5f * xs[2]);
            const float bx0 = fmaf(cw2, xg[0], 0.5f * xq[0]);
            const float bx1 = fmaf(cw2, xg[1], 0.5f * xq[1]);
            const float bx2 = fmaf(cw2, xg[2], 0.5f * xq[2]);
            char* fragW = sFrag[buf] + ((p >> 2) * 2 + s) * TSTRIDE
                        + (4 * g4 + (p & 3)) * 16;
            #pragma unroll
            for (int q = 0; q < 4; ++q) {
                unsigned dws[4];
                #pragma unroll
                for (int pr = 0; pr < 4; ++pr) {
                    float azv[2];
                    #pragma unroll
                    for (int e = 0; e < 2; ++e) {
                        const float4 wv = sW1B[k0q + q*8 + pr*2 + e];
                        float ts = fmaf(ax0, wv.x, wv.w);
                        ts = fmaf(ax1, wv.y, ts);
                        ts = fmaf(ax2, wv.z, ts);
                        ts = fmaxf(ts, 0.f);
                        float tp = fmaf(bx0, wv.x, wv.w);
                        tp = fmaf(bx1, wv.y, tp);
                        tp = fmaf(bx2, wv.z, tp);
                        tp = fmaxf(tp, 0.f);
                        azv[e] = fmaf(cw, tp, 0.5f * ts);
                    }
                    dws[pr] = __builtin_amdgcn_perm(__float_as_uint(azv[1]),
                                                    __float_as_uint(azv[0]),
                                                    0x07060302u);
                }
                *(uint4*)(fragW + q * 256) =
                    make_uint4(dws[0], dws[1], dws[2], dws[3]);
            }
        }
    };

    // ---- prologue ----
    if (tid < 64) sW1B[tid] = ((const float4*)ws)[tid];
    #pragma unroll
    for (int i = tid; i < 264; i += 256) {          // zero pad tiles (m=5), both bufs
        const int b = (i >= 132) ? 1 : 0;
        const int off = i - b * 132;
        *(float4*)(sFrag[b] + 10 * TSTRIDE + off * 16) =
            make_float4(0.f, 0.f, 0.f, 0.f);
    }
    float4 xr0, xr1, xreg;
    if (tid < 63) {
        xr0  = ((const float4*)(x + cbase * 252))[tid];
        xr1  = ((const float4*)(x + (cbase + 1) * 252))[tid];
        xreg = ((const float4*)(x + (cbase + 2) * 252))[tid];
        sX[0][tid] = xr0;
    }
    __syncthreads();
    phase1(0);
    if (tid < 63) sX[1][tid] = xr1;
    __syncthreads();

    // ---- chunk loop: 2 barriers per chunk ----
    for (int ck = 0; ck < CPB; ++ck) {
        const int cur = ck & 1;

        // ======== interval A: ph2[ck] (MFMA+epilogue) || ph1[ck+1] (VALU) ====
        {
            const char* fragA = sFrag[cur] + lane * 16;
            float pg0 = 0.f, pg1 = 0.f;
            #pragma unroll
            for (int m = 0; m < 6; ++m) {
                const s16x8 A0 = *(const s16x8*)(fragA + (2*m + 0) * TSTRIDE);
                const s16x8 A1 = *(const s16x8*)(fragA + (2*m + 1) * TSTRIDE);
                f32x4 acc0 = {0.f, 0.f, 0.f, 0.f};
                f32x4 acc1 = {0.f, 0.f, 0.f, 0.f};
                acc0 = __builtin_amdgcn_mfma_f32_16x16x32_bf16(A0, *(const s16x8*)&B00, acc0, 0, 0, 0);
                acc0 = __builtin_amdgcn_mfma_f32_16x16x32_bf16(A1, *(const s16x8*)&B01, acc0, 0, 0, 0);
                acc1 = __builtin_amdgcn_mfma_f32_16x16x32_bf16(A0, *(const s16x8*)&B10, acc1, 0, 0, 0);
                acc1 = __builtin_amdgcn_mfma_f32_16x16x32_bf16(A1, *(const s16x8*)&B11, acc1, 0, 0, 0);
                #pragma unroll
                for (int i = 0; i < 4; ++i) {
                    const int p = 4*m + i;
                    if (p < 21) {
                        const float wgt = (p == 0) ? ROOT_W
                                        : (((p & 3) == 0) ? (0.5f / 21.f) : (1.f / 21.f));
                        pg0 = fmaf(wgt, fmaxf(acc0[i] + b2c0, 0.f), pg0);
                        pg1 = fmaf(wgt, fmaxf(acc1[i] + b2c1, 0.f), pg1);
                    }
                }
            }
            sPool[lg * 132 + 32*w + r]      = pg0;
            sPool[lg * 132 + 32*w + 16 + r] = pg1;

            if (ck < CPB - 1) phase1(cur ^ 1);
        }
        __syncthreads();

        // ======== interval B: ph3[ck] + softmax + out; x pipeline ============
        {
            float v = -1e30f;
            if (lane < 2 * NCLS) {
                const float4* pp = (const float4*)&sPool[w * 132 + 64 * h3];
                const float4* w3 = (const float4*)w3base;
                float acc3 = 0.f;
                #pragma unroll
                for (int q = 0; q < 16; ++q) {
                    const float4 pv = pp[q];
                    const float4 wv = w3[q];
                    acc3 = fmaf(pv.x, wv.x, acc3);
                    acc3 = fmaf(pv.y, wv.y, acc3);
                    acc3 = fmaf(pv.z, wv.z, acc3);
                    acc3 = fmaf(pv.w, wv.w, acc3);
                }
                v = acc3;
            }
            v += __shfl_xor(v, 1);              // both halves -> full 128-dot
            if (lane < 2 * NCLS) v += b3r;
            float m = v;
            m = fmaxf(m, __shfl_xor(m, 2));
            m = fmaxf(m, __shfl_xor(m, 4));
            m = fmaxf(m, __shfl_xor(m, 8));
            m = fmaxf(m, __shfl_xor(m, 16));
            m = fmaxf(m, __shfl_xor(m, 32));
            float e = (lane < 2 * NCLS) ? __expf(v - m) : 0.f;
            float ss = e;
            ss += __shfl_xor(ss, 2);
            ss += __shfl_xor(ss, 4);
            ss += __shfl_xor(ss, 8);
            ss += __shfl_xor(ss, 16);
            ss += __shfl_xor(ss, 32);
            if (h3 == 0 && lane < 2 * NCLS)
                out[((cbase + ck) * GPB + w) * NCLS + cc] = v - m - __logf(ss);

            if (tid < 63) {
                if (ck <= CPB - 3) sX[cur][tid] = xreg;                 // x[ck+2]
                if (ck <= CPB - 4)
                    xreg = ((const float4*)(x + (cbase + ck + 3) * 252))[tid];
            }
        }
        __syncthreads();
    }
}

extern "C" void kernel_launch(void* const* d_in, const int* in_sizes, int n_in,
                              void* d_out, int out_size, void* d_ws, size_t ws_size,
                              hipStream_t stream) {
    const float* x   = (const float*)d_in[0];
    const float* W1  = (const float*)d_in[1];
    const float* b1  = (const float*)d_in[2];
    const float* g1  = (const float*)d_in[3];
    const float* be1 = (const float*)d_in[4];
    const float* m1  = (const float*)d_in[5];
    const float* v1  = (const float*)d_in[6];
    const float* W2  = (const float*)d_in[7];
    const float* b2  = (const float*)d_in[8];
    const float* g2  = (const float*)d_in[9];
    const float* be2 = (const float*)d_in[10];
    const float* m2  = (const float*)d_in[11];
    const float* v2  = (const float*)d_in[12];
    const float* W3  = (const float*)d_in[13];
    const float* b3  = (const float*)d_in[14];
    float* out = (float*)d_out;
    float* ws  = (float*)d_ws;

    prep_kernel<<<(WS_TOTAL + 255) / 256, 256, 0, stream>>>(
        W1, b1, g1, be1, m1, v1, W2, b2, g2, be2, m2, v2, W3, b3, ws);

    gcn_main<<<NBLK, 256, 0, stream>>>(x, ws, out);
}